// Round 9
// baseline (152.298 us; speedup 1.0000x reference)
//
#include <hip/hip_runtime.h>
#include <hip/hip_bf16.h>

// Problem constants
#define BDIM 8
#define NNODE 2048
#define CIN 256
#define NEDGE 32768
#define NHEAD 8
#define COUT 64
#define HC 512            // NHEAD * COUT
#define BN_TOT 16384      // BDIM * NNODE
#define NEG_SLOPE 0.2f
#define NHIST 32          // partial-histogram blocks

typedef __hip_bfloat16 bf16;
typedef __attribute__((ext_vector_type(8))) short bfrag;   // 8 bf16 = 4 VGPRs
typedef __attribute__((ext_vector_type(4))) float ffrag;   // 4 fp32 acc

static __device__ __forceinline__ short f2b(float f) {
    __hip_bfloat16 h = __float2bfloat16(f);
    return *(short*)&h;
}
static __device__ __forceinline__ float b2f(short s) {
    return __uint_as_float(((unsigned)(unsigned short)s) << 16);
}
static __device__ __forceinline__ unsigned pack2(float a, float b) {
    return (unsigned)(unsigned short)f2b(a) | ((unsigned)(unsigned short)f2b(b) << 16);
}
// async global->LDS, 16B per lane; LDS dest = wave-uniform base + lane*16
static __device__ __forceinline__ void async_cp16(const short* gsrc, short* ldst) {
    __builtin_amdgcn_global_load_lds(
        (const __attribute__((address_space(1))) void*)gsrc,
        (__attribute__((address_space(3))) void*)ldst, 16, 0, 0);
}

// ---------------------------------------------------------------------------
// Kernel 1 (fused prep): W transpose -> WT bf16; x -> xbf; 32 partial
// histograms (round-8 structure, worked: no serial straggler).
// ---------------------------------------------------------------------------
__global__ __launch_bounds__(256) void prep_kernel(const float* __restrict__ x,
                                                   const float* __restrict__ W,
                                                   const int* __restrict__ ei,
                                                   short* __restrict__ xbf,
                                                   short* __restrict__ WT,
                                                   int* __restrict__ cnt_part) {
    const int b = blockIdx.x;
    if (b < 128) {
        __shared__ float t[32][33];
        const int kt = b >> 4;
        const int nt = b & 15;
        const int tx = threadIdx.x & 31, ty = threadIdx.x >> 5;
#pragma unroll
        for (int i = 0; i < 4; ++i)
            t[ty + 8 * i][tx] = W[(kt * 32 + ty + 8 * i) * HC + nt * 32 + tx];
        __syncthreads();
#pragma unroll
        for (int i = 0; i < 4; ++i)
            WT[(nt * 32 + ty + 8 * i) * CIN + kt * 32 + tx] = f2b(t[tx][ty + 8 * i]);
    } else if (b < 2176) {
        const int t = (b - 128) * 256 + threadIdx.x;
        const float4* px = (const float4*)x;
        float4 v0 = px[t * 2], v1 = px[t * 2 + 1];
        bfrag o;
        o[0] = f2b(v0.x); o[1] = f2b(v0.y); o[2] = f2b(v0.z); o[3] = f2b(v0.w);
        o[4] = f2b(v1.x); o[5] = f2b(v1.y); o[6] = f2b(v1.z); o[7] = f2b(v1.w);
        *(bfrag*)&xbf[t * 8] = o;
    } else {
        __shared__ int hcnt[NNODE];
        const int p = b - 2176;
        const int t = threadIdx.x;
        for (int k = t; k < NNODE; k += 256) hcnt[k] = 0;
        __syncthreads();
        const int* dst = ei + NEDGE;
        const int base = p * (NEDGE / NHIST);
#pragma unroll
        for (int k = 0; k < NEDGE / NHIST / 256; ++k)
            atomicAdd(&hcnt[dst[base + t + k * 256]], 1);
        __syncthreads();
        for (int k = t; k < NNODE; k += 256) cnt_part[k * NHIST + p] = hcnt[k];
    }
}

// ---------------------------------------------------------------------------
// Kernel 2: single-block CSR finalize (unchanged from round 8).
// ---------------------------------------------------------------------------
__global__ __launch_bounds__(256) void scan_kernel(const int* __restrict__ cnt_part,
                                                   int* __restrict__ cnt,
                                                   int* __restrict__ rowptr0,
                                                   int* __restrict__ widx) {
    __shared__ int sums[256];
    const int t = threadIdx.x;
    int v[8];
    int tot = 0;
#pragma unroll
    for (int i = 0; i < 8; ++i) {
        const int n = t * 8 + i;
        int s = 0;
#pragma unroll
        for (int p4 = 0; p4 < NHIST; p4 += 4) {
            int4 c = *(const int4*)&cnt_part[n * NHIST + p4];
            s += c.x + c.y + c.z + c.w;
        }
        v[i] = s;
        tot += s;
    }
    sums[t] = tot;
    __syncthreads();
    for (int off = 1; off < 256; off <<= 1) {
        int xv = (t >= off) ? sums[t - off] : 0;
        __syncthreads();
        sums[t] += xv;
        __syncthreads();
    }
    int run = sums[t] - tot;
    int base[8];
#pragma unroll
    for (int i = 0; i < 8; ++i) { base[i] = run; run += v[i]; }
#pragma unroll
    for (int i = 0; i < 8; ++i) {
        const int n = t * 8 + i;
        cnt[n] = v[i];
        rowptr0[n] = base[i];
    }
#pragma unroll
    for (int b2 = 0; b2 < BDIM; ++b2)
#pragma unroll
        for (int i = 0; i < 8; ++i)
            widx[b2 * NNODE + t * 8 + i] = b2 * NEDGE + base[i];
}

// ---------------------------------------------------------------------------
// Kernel 3 (fused): blocks 0..511 = bf16 MFMA GEMM with fused att-score
// epilogue; blocks 512..1535 = edge scatter (independent, overlapped).
//
// GEMM: 128x128 tile, BK=32, 4 waves x (64 nodes x 64 channels).
// Staging via global_load_lds width=16, k-major blocked LDS layout:
//   phys(row, kc) = (row>>4)*1024B + kc*256B + (row&15)*16B
// -> staging: lane l of issue i writes base+(l*16) exactly (HW constraint);
// -> frag ds_read_b128: 64 lanes hit 64 distinct 16B chunks = conflict-free.
// MFMA with SWAPPED operands: mfma(b_frag, a_frag) => lane&15 = node,
// reg quad*4+r = 4 CONSECUTIVE channels -> 8B packed bf16 stores (16/thread
// vs 64 scalar 2B stores before), and per-node/head att dots reduce with
// 2 shfl_xor (head = fully contained in this block's 64-col wave slice).
// ---------------------------------------------------------------------------
__global__ __launch_bounds__(256) void gemm_scatter(const short* __restrict__ xbf,
                                                    const short* __restrict__ WT,
                                                    short* __restrict__ xtb,
                                                    const float* __restrict__ att_src,
                                                    const float* __restrict__ att_dst,
                                                    float* __restrict__ ssrc,
                                                    float* __restrict__ sdst,
                                                    const int* __restrict__ ei,
                                                    int* __restrict__ widx,
                                                    int* __restrict__ col) {
    const int blk = blockIdx.x;
    if (blk >= 512) {
        const int t = (blk - 512) * 256 + threadIdx.x;   // 0..262143
        const int b = t >> 15;
        const int e = t & (NEDGE - 1);
        const int s = ei[e];
        const int d = ei[NEDGE + e];
        const int p = atomicAdd(&widx[b * NNODE + d], 1);
        col[p] = b * NNODE + s;
        return;
    }

    __shared__ __align__(16) short As[128 * 32];   // 8 KB, k-major blocked
    __shared__ __align__(16) short Bs[128 * 32];   // 8 KB

    const int tid  = threadIdx.x;
    const int row0 = (blk >> 2) * 128;             // node tile
    const int col0 = (blk & 3) * 128;              // channel tile (2 heads)
    const int w    = tid >> 6;
    const int lane = tid & 63;
    const int wm   = (w & 1) * 64;                 // node half
    const int wn   = (w >> 1) * 64;                // channel half (1 head)
    const int fm   = lane & 15;
    const int fq   = lane >> 4;
    const int l15  = lane & 15;                    // staging row-within-16
    const int lkc  = lane >> 4;                    // staging k-chunk

    ffrag acc[4][4] = {};   // acc[ng][mg]: rows=channels, cols=nodes (swapped)

    for (int k0 = 0; k0 < CIN; k0 += 32) {
        __syncthreads();   // previous iteration's frag reads complete
        // A: wave w stages node rows [w*32, w*32+32), 2 issues of 16 rows
        // B: same for channel rows of WT
#pragma unroll
        for (int i = 0; i < 2; ++i) {
            const int r16 = w * 32 + i * 16;
            async_cp16(&xbf[(row0 + r16 + l15) * CIN + k0 + lkc * 8],
                       &As[(w * 2 + i) * 512]);
            async_cp16(&WT[(col0 + r16 + l15) * CIN + k0 + lkc * 8],
                       &Bs[(w * 2 + i) * 512]);
        }
        __syncthreads();   // drains vmcnt (global_load_lds) before reads

        bfrag af[4], bfr[4];
#pragma unroll
        for (int g = 0; g < 4; ++g) {
            af[g]  = *(const bfrag*)&As[((wm >> 4) + g) * 512 + fq * 128 + fm * 8];
            bfr[g] = *(const bfrag*)&Bs[((wn >> 4) + g) * 512 + fq * 128 + fm * 8];
        }
#pragma unroll
        for (int ng = 0; ng < 4; ++ng)
#pragma unroll
            for (int mg = 0; mg < 4; ++mg)
                acc[ng][mg] = __builtin_amdgcn_mfma_f32_16x16x32_bf16(
                    bfr[ng], af[mg], acc[ng][mg], 0, 0, 0);
    }

    // ---- epilogue: packed bf16 stores + fused attention scores ----
    // lane holds: node nd = row0+wm+mg*16+fm, channels cb..cb+3,
    // cb = col0+wn+ng*16+fq*4.
    float4 s4[4], d4[4];
#pragma unroll
    for (int ng = 0; ng < 4; ++ng) {
        const int cb = col0 + wn + ng * 16 + fq * 4;
        s4[ng] = *(const float4*)&att_src[cb];
        d4[ng] = *(const float4*)&att_dst[cb];
    }
    const int head = (col0 + wn) >> 6;
#pragma unroll
    for (int mg = 0; mg < 4; ++mg) {
        const int nd = row0 + wm + mg * 16 + fm;
        float ps = 0.f, pd = 0.f;
#pragma unroll
        for (int ng = 0; ng < 4; ++ng) {
            const int cb = col0 + wn + ng * 16 + fq * 4;
            uint2 pk;
            pk.x = pack2(acc[ng][mg][0], acc[ng][mg][1]);
            pk.y = pack2(acc[ng][mg][2], acc[ng][mg][3]);
            *(uint2*)&xtb[nd * HC + cb] = pk;
            ps += acc[ng][mg][0] * s4[ng].x + acc[ng][mg][1] * s4[ng].y +
                  acc[ng][mg][2] * s4[ng].z + acc[ng][mg][3] * s4[ng].w;
            pd += acc[ng][mg][0] * d4[ng].x + acc[ng][mg][1] * d4[ng].y +
                  acc[ng][mg][2] * d4[ng].z + acc[ng][mg][3] * d4[ng].w;
        }
        ps += __shfl_xor(ps, 16); ps += __shfl_xor(ps, 32);
        pd += __shfl_xor(pd, 16); pd += __shfl_xor(pd, 32);
        if (lane < 16) {
            ssrc[nd * NHEAD + head] = ps;
            sdst[nd * NHEAD + head] = pd;
        }
    }
}

// ---------------------------------------------------------------------------
// Kernel 4: merged-head aggregation (unchanged from round 8).
// ---------------------------------------------------------------------------
__global__ __launch_bounds__(256) void aggregate(const short* __restrict__ xtb,
                                                 const float* __restrict__ ssrc,
                                                 const float* __restrict__ sdst,
                                                 const int* __restrict__ cnt,
                                                 const int* __restrict__ rowptr0,
                                                 const int* __restrict__ col,
                                                 const float* __restrict__ bias,
                                                 float* __restrict__ out) {
    __shared__ float wlds[4][NHEAD][68];
    __shared__ int   jlds[4][64];
    const int nb   = threadIdx.x >> 6;
    const int lane = threadIdx.x & 63;
    const int blk  = blockIdx.x;
    const int bidx = blk & 7;                                   // batch -> XCD
    const int i    = bidx * NNODE + (blk >> 3) * 4 + nb;
    const int n    = i & (NNODE - 1);
    const int deg  = cnt[n];
    const int start = bidx * NEDGE + rowptr0[n];
    const int h    = lane >> 3;
    const int sub  = lane & 7;
    float* wrow = &wlds[nb][0][0];
    int*   jrow = &jlds[nb][0];

    for (int t = lane; t < NHEAD * 68; t += 64) wrow[t] = 0.f;
    jrow[lane] = i;

    const float sdh = sdst[i * NHEAD + h];
    float selfv = ssrc[i * NHEAD + h] + sdh;
    selfv = selfv >= 0.f ? selfv : NEG_SLOPE * selfv;

    float m = selfv;
    for (int e = sub; e < deg; e += 8) {
        int j = col[start + e];
        float v = ssrc[j * NHEAD + h] + sdh;
        v = v >= 0.f ? v : NEG_SLOPE * v;
        if (e < 64) {
            wrow[h * 68 + e] = v;
            if (h == 0) jrow[e] = j;
        }
        m = fmaxf(m, v);
    }
    m = fmaxf(m, __shfl_xor(m, 4));
    m = fmaxf(m, __shfl_xor(m, 2));
    m = fmaxf(m, __shfl_xor(m, 1));

    float sp = 0.f;
    for (int e = sub; e < deg; e += 8) {
        float v;
        if (e < 64) {
            v = wrow[h * 68 + e];
        } else {
            int j = col[start + e];
            v = ssrc[j * NHEAD + h] + sdh;
            v = v >= 0.f ? v : NEG_SLOPE * v;
        }
        float w = __expf(v - m);
        if (e < 64) wrow[h * 68 + e] = w;
        sp += w;
    }
    sp += __shfl_xor(sp, 4); sp += __shfl_xor(sp, 2); sp += __shfl_xor(sp, 1);
    const float eself = __expf(selfv - m);
    const float inv = 1.f / (sp + eself + 1e-16f);

    const int c8 = lane * 8;
    float acc[8] = {};

    // self-loop
    {
        bfrag xv = *(const bfrag*)&xtb[i * HC + c8];
#pragma unroll
        for (int k = 0; k < 8; ++k) acc[k] += eself * b2f(xv[k]);
    }

    const int degc = min(deg, 64);
    const int degp = (degc + 7) & ~7;
    for (int e0 = 0; e0 < degp; e0 += 8) {
        float4 wA = *(const float4*)&wrow[h * 68 + e0];
        float4 wB = *(const float4*)&wrow[h * 68 + e0 + 4];
        int4 jA = *(const int4*)&jrow[e0];
        int4 jB = *(const int4*)&jrow[e0 + 4];
        bfrag x0 = *(const bfrag*)&xtb[jA.x * HC + c8];
        bfrag x1 = *(const bfrag*)&xtb[jA.y * HC + c8];
        bfrag x2 = *(const bfrag*)&xtb[jA.z * HC + c8];
        bfrag x3 = *(const bfrag*)&xtb[jA.w * HC + c8];
        bfrag x4 = *(const bfrag*)&xtb[jB.x * HC + c8];
        bfrag x5 = *(const bfrag*)&xtb[jB.y * HC + c8];
        bfrag x6 = *(const bfrag*)&xtb[jB.z * HC + c8];
        bfrag x7 = *(const bfrag*)&xtb[jB.w * HC + c8];
#pragma unroll
        for (int k = 0; k < 8; ++k) {
            acc[k] += wA.x * b2f(x0[k]) + wA.y * b2f(x1[k]) +
                      wA.z * b2f(x2[k]) + wA.w * b2f(x3[k]) +
                      wB.x * b2f(x4[k]) + wB.y * b2f(x5[k]) +
                      wB.z * b2f(x6[k]) + wB.w * b2f(x7[k]);
        }
    }
    // correctness fallback for deg > 64
    for (int e = 64; e < deg; ++e) {
        int j = col[start + e];
        float v = ssrc[j * NHEAD + h] + sdh;
        v = v >= 0.f ? v : NEG_SLOPE * v;
        float wv = __expf(v - m);
        bfrag xv = *(const bfrag*)&xtb[j * HC + c8];
#pragma unroll
        for (int k = 0; k < 8; ++k) acc[k] += wv * b2f(xv[k]);
    }

    const float4 b0 = *(const float4*)&bias[c8];
    const float4 b1 = *(const float4*)&bias[c8 + 4];
    float4 o0 = {acc[0] * inv + b0.x, acc[1] * inv + b0.y,
                 acc[2] * inv + b0.z, acc[3] * inv + b0.w};
    float4 o1 = {acc[4] * inv + b1.x, acc[5] * inv + b1.y,
                 acc[6] * inv + b1.z, acc[7] * inv + b1.w};
    *(float4*)&out[i * HC + c8]     = o0;
    *(float4*)&out[i * HC + c8 + 4] = o1;
}

// ---------------------------------------------------------------------------
extern "C" void kernel_launch(void* const* d_in, const int* in_sizes, int n_in,
                              void* d_out, int out_size, void* d_ws, size_t ws_size,
                              hipStream_t stream) {
    const float* x       = (const float*)d_in[0];
    const int*   ei      = (const int*)d_in[1];
    const float* W       = (const float*)d_in[2];
    const float* att_src = (const float*)d_in[3];
    const float* att_dst = (const float*)d_in[4];
    const float* bias    = (const float*)d_in[5];
    float* out = (float*)d_out;

    char* ws = (char*)d_ws;
    short* xtb      = (short*)(ws);                                // 16777216 B
    float* ssrc     = (float*)(ws + 16777216);                     // 524288 B
    float* sdst     = (float*)(ws + 17301504);                     // 524288 B
    int*   cnt      = (int*)(ws + 17825792);                       // 8192 B
    int*   rowptr0  = (int*)(ws + 17833984);                       // 8192 B
    int*   widx     = (int*)(ws + 17842176);                       // 65536 B
    int*   col      = (int*)(ws + 17907712);                       // 1048576 B
    short* xbf      = (short*)(ws + 18956288);                     // 8388608 B
    short* WT       = (short*)(ws + 27344896);                     // 262144 B
    int*   cnt_part = (int*)(ws + 27607040);                       // 262144 B
                                                                   // total 27869184 B
    prep_kernel<<<2176 + NHIST, 256, 0, stream>>>(x, W, ei, xbf, WT, cnt_part);
    scan_kernel<<<1, 256, 0, stream>>>(cnt_part, cnt, rowptr0, widx);
    gemm_scatter<<<1536, 256, 0, stream>>>(xbf, WT, xtb, att_src, att_dst,
                                           ssrc, sdst, ei, widx, col);
    aggregate<<<BN_TOT / 4, 256, 0, stream>>>(xtb, ssrc, sdst, cnt, rowptr0, col, bias, out);
}

// Round 10
// 148.594 us; speedup vs baseline: 1.0249x; 1.0249x over previous
//
#include <hip/hip_runtime.h>
#include <hip/hip_bf16.h>

// Problem constants
#define BDIM 8
#define NNODE 2048
#define CIN 256
#define NEDGE 32768
#define NHEAD 8
#define COUT 64
#define HC 512            // NHEAD * COUT
#define BN_TOT 16384      // BDIM * NNODE
#define NEG_SLOPE 0.2f
#define NHIST 32          // partial-histogram blocks
#define GEMM_BLKS 256     // 64-row x 512-col tiles

typedef __hip_bfloat16 bf16;
typedef __attribute__((ext_vector_type(8))) short bfrag;   // 8 bf16 = 4 VGPRs
typedef __attribute__((ext_vector_type(4))) float ffrag;   // 4 fp32 acc

static __device__ __forceinline__ short f2b(float f) {
    __hip_bfloat16 h = __float2bfloat16(f);
    return *(short*)&h;
}
static __device__ __forceinline__ float b2f(short s) {
    return __uint_as_float(((unsigned)(unsigned short)s) << 16);
}
static __device__ __forceinline__ unsigned pack2(float a, float b) {
    return (unsigned)(unsigned short)f2b(a) | ((unsigned)(unsigned short)f2b(b) << 16);
}
// async global->LDS, 16B/lane; LDS dest = wave-uniform base + lane*16
static __device__ __forceinline__ void async_cp16(const short* gsrc, short* ldst) {
    __builtin_amdgcn_global_load_lds(
        (const __attribute__((address_space(1))) void*)gsrc,
        (__attribute__((address_space(3))) void*)ldst, 16, 0, 0);
}

// ---------------------------------------------------------------------------
// Kernel 1 (small prep): blocks 0..127 transpose W -> WT bf16 [512][256];
// blocks 128..159: partial histograms (r8 structure — no serial straggler).
// x conversion is GONE (folded into the GEMM's A-staging).
// ---------------------------------------------------------------------------
__global__ __launch_bounds__(256) void prep_kernel(const float* __restrict__ W,
                                                   const int* __restrict__ ei,
                                                   short* __restrict__ WT,
                                                   int* __restrict__ cnt_part) {
    const int b = blockIdx.x;
    if (b < 128) {
        __shared__ float t[32][33];
        const int kt = b >> 4;
        const int nt = b & 15;
        const int tx = threadIdx.x & 31, ty = threadIdx.x >> 5;
#pragma unroll
        for (int i = 0; i < 4; ++i)
            t[ty + 8 * i][tx] = W[(kt * 32 + ty + 8 * i) * HC + nt * 32 + tx];
        __syncthreads();
#pragma unroll
        for (int i = 0; i < 4; ++i)
            WT[(nt * 32 + ty + 8 * i) * CIN + kt * 32 + tx] = f2b(t[tx][ty + 8 * i]);
    } else {
        __shared__ int hcnt[NNODE];
        const int p = b - 128;
        const int t = threadIdx.x;
        for (int k = t; k < NNODE; k += 256) hcnt[k] = 0;
        __syncthreads();
        const int* dst = ei + NEDGE;
        const int base = p * (NEDGE / NHIST);
#pragma unroll
        for (int k = 0; k < NEDGE / NHIST / 256; ++k)
            atomicAdd(&hcnt[dst[base + t + k * 256]], 1);
        __syncthreads();
        for (int k = t; k < NNODE; k += 256) cnt_part[k * NHIST + p] = hcnt[k];
    }
}

// ---------------------------------------------------------------------------
// Kernel 2: single-block CSR finalize (unchanged).
// ---------------------------------------------------------------------------
__global__ __launch_bounds__(256) void scan_kernel(const int* __restrict__ cnt_part,
                                                   int* __restrict__ cnt,
                                                   int* __restrict__ rowptr0,
                                                   int* __restrict__ widx) {
    __shared__ int sums[256];
    const int t = threadIdx.x;
    int v[8];
    int tot = 0;
#pragma unroll
    for (int i = 0; i < 8; ++i) {
        const int n = t * 8 + i;
        int s = 0;
#pragma unroll
        for (int p4 = 0; p4 < NHIST; p4 += 4) {
            int4 c = *(const int4*)&cnt_part[n * NHIST + p4];
            s += c.x + c.y + c.z + c.w;
        }
        v[i] = s;
        tot += s;
    }
    sums[t] = tot;
    __syncthreads();
    for (int off = 1; off < 256; off <<= 1) {
        int xv = (t >= off) ? sums[t - off] : 0;
        __syncthreads();
        sums[t] += xv;
        __syncthreads();
    }
    int run = sums[t] - tot;
    int base[8];
#pragma unroll
    for (int i = 0; i < 8; ++i) { base[i] = run; run += v[i]; }
#pragma unroll
    for (int i = 0; i < 8; ++i) {
        const int n = t * 8 + i;
        cnt[n] = v[i];
        rowptr0[n] = base[i];
    }
#pragma unroll
    for (int b2 = 0; b2 < BDIM; ++b2)
#pragma unroll
        for (int i = 0; i < 8; ++i)
            widx[b2 * NNODE + t * 8 + i] = b2 * NEDGE + base[i];
}

// ---------------------------------------------------------------------------
// Kernel 3 (fused): blocks 0..255 = full-width GEMM tile (64 nodes x 512
// channels) reading fp32 x DIRECTLY (each x byte crosses the bus once; no
// xbf intermediate). Blocks 256..767 = edge scatter (overlapped).
//
// Per gemm block (512 threads = 8 waves; wave = 32 rows x 128 cols):
//   A: fp32 x -> bf16 LDS once (32 KB, blocked layout
//      idx16B(row,kc) = rb*... (rb=row>>4)*32+kc)*16+(row&15) -> frag
//      ds_read_b128 is 1024B-contiguous per wave = conflict-free).
//   B: WT streamed in 32-K chunks via global_load_lds, DOUBLE-BUFFERED
//      (one __syncthreads per K-iter; barrier drains vmcnt).
//   MFMA swapped operands (r9-verified): lane&15 = node, reg = 4 consecutive
//   channels -> packed 8B stores + fused att-score dots (2 heads/wave).
// ---------------------------------------------------------------------------
__global__ __launch_bounds__(512, 2) void gemm_scatter(const float* __restrict__ x,
                                                       const short* __restrict__ WT,
                                                       short* __restrict__ xtb,
                                                       const float* __restrict__ att_src,
                                                       const float* __restrict__ att_dst,
                                                       float* __restrict__ ssrc,
                                                       float* __restrict__ sdst,
                                                       const int* __restrict__ ei,
                                                       int* __restrict__ widx,
                                                       int* __restrict__ col) {
    const int blk = blockIdx.x;
    if (blk >= GEMM_BLKS) {
        const int t = (blk - GEMM_BLKS) * 512 + threadIdx.x;   // 0..262143
        const int b = t >> 15;
        const int e = t & (NEDGE - 1);
        const int s = ei[e];
        const int d = ei[NEDGE + e];
        const int p = atomicAdd(&widx[b * NNODE + d], 1);
        col[p] = b * NNODE + s;
        return;
    }

    __shared__ __align__(16) short As[64 * 256];        // 32 KB
    __shared__ __align__(16) short Bs[2][512 * 32];     // 2 x 32 KB

    const int tid  = threadIdx.x;
    const int lane = tid & 63;
    const int w    = tid >> 6;            // 0..7
    const int row0 = blk * 64;
    const int wm   = (w & 1) * 32;        // row half (32 rows)
    const int wn   = (w >> 1) * 128;      // col quarter (128 ch = 2 heads)
    const int fm   = lane & 15;
    const int fq   = lane >> 4;

    // ---- stage A: fp32 x -> bf16 LDS (once) ----
    {
        const int r   = tid >> 3;             // 0..63
        const int kb0 = (tid & 7) * 8;        // 0..56
#pragma unroll
        for (int i = 0; i < 4; ++i) {
            const int kb = kb0 + i * 64;
            float4 v0 = *(const float4*)&x[(row0 + r) * CIN + kb];
            float4 v1 = *(const float4*)&x[(row0 + r) * CIN + kb + 4];
            bfrag o;
            o[0] = f2b(v0.x); o[1] = f2b(v0.y); o[2] = f2b(v0.z); o[3] = f2b(v0.w);
            o[4] = f2b(v1.x); o[5] = f2b(v1.y); o[6] = f2b(v1.z); o[7] = f2b(v1.w);
            *(bfrag*)&As[(((r >> 4) * 32 + (kb >> 3)) * 16 + (r & 15)) * 8] = o;
        }
    }

    // ---- first B chunk (k0 = 0) into buf 0 ----
    // wave w issues 4 groups of 16 channels; layout idx16B = cb16*64 + lane
    {
#pragma unroll
        for (int i2 = 0; i2 < 4; ++i2) {
            const int cb16 = w * 4 + i2;
            const int c = cb16 * 16 + (lane >> 2);
            async_cp16(&WT[c * CIN + (lane & 3) * 8], &Bs[0][cb16 * 512]);
        }
    }
    __syncthreads();   // A writes visible + chunk0 drained (barrier waits vmcnt)

    ffrag acc[8][2] = {};   // [ng][mg]

    for (int k8 = 0; k8 < 8; ++k8) {
        const int buf = k8 & 1;
        if (k8 < 7) {
            const int k0n = (k8 + 1) * 32;
#pragma unroll
            for (int i2 = 0; i2 < 4; ++i2) {
                const int cb16 = w * 4 + i2;
                const int c = cb16 * 16 + (lane >> 2);
                async_cp16(&WT[c * CIN + k0n + (lane & 3) * 8], &Bs[buf ^ 1][cb16 * 512]);
            }
        }
        bfrag af[2];
#pragma unroll
        for (int mg = 0; mg < 2; ++mg)
            af[mg] = *(const bfrag*)&As[((((wm >> 4) + mg) * 32 + k8 * 4 + fq) * 16 + fm) * 8];
#pragma unroll
        for (int ng = 0; ng < 8; ++ng) {
            bfrag bfr = *(const bfrag*)&Bs[buf][((((wn >> 4) + ng) * 16 + fm) * 4 + fq) * 8];
#pragma unroll
            for (int mg = 0; mg < 2; ++mg)
                acc[ng][mg] = __builtin_amdgcn_mfma_f32_16x16x32_bf16(
                    bfr, af[mg], acc[ng][mg], 0, 0, 0);
        }
        __syncthreads();   // all waves done with Bs[buf]; next chunk drained
    }

    // ---- epilogue: packed bf16 stores + fused attention scores ----
    float4 s4[8], d4[8];
#pragma unroll
    for (int ng = 0; ng < 8; ++ng) {
        const int cb = wn + ng * 16 + fq * 4;
        s4[ng] = *(const float4*)&att_src[cb];
        d4[ng] = *(const float4*)&att_dst[cb];
    }
    const int head0 = wn >> 6;            // heads head0, head0+1
#pragma unroll
    for (int mg = 0; mg < 2; ++mg) {
        const int nd = row0 + wm + mg * 16 + fm;
        float ps0 = 0.f, pd0 = 0.f, ps1 = 0.f, pd1 = 0.f;
#pragma unroll
        for (int ng = 0; ng < 8; ++ng) {
            const int cb = wn + ng * 16 + fq * 4;
            uint2 pk;
            pk.x = pack2(acc[ng][mg][0], acc[ng][mg][1]);
            pk.y = pack2(acc[ng][mg][2], acc[ng][mg][3]);
            *(uint2*)&xtb[nd * HC + cb] = pk;
            const float dot_s = acc[ng][mg][0] * s4[ng].x + acc[ng][mg][1] * s4[ng].y +
                                acc[ng][mg][2] * s4[ng].z + acc[ng][mg][3] * s4[ng].w;
            const float dot_d = acc[ng][mg][0] * d4[ng].x + acc[ng][mg][1] * d4[ng].y +
                                acc[ng][mg][2] * d4[ng].z + acc[ng][mg][3] * d4[ng].w;
            if (ng < 4) { ps0 += dot_s; pd0 += dot_d; }
            else        { ps1 += dot_s; pd1 += dot_d; }
        }
        ps0 += __shfl_xor(ps0, 16); ps0 += __shfl_xor(ps0, 32);
        pd0 += __shfl_xor(pd0, 16); pd0 += __shfl_xor(pd0, 32);
        ps1 += __shfl_xor(ps1, 16); ps1 += __shfl_xor(ps1, 32);
        pd1 += __shfl_xor(pd1, 16); pd1 += __shfl_xor(pd1, 32);
        if (lane < 16) {
            ssrc[nd * NHEAD + head0]     = ps0;
            sdst[nd * NHEAD + head0]     = pd0;
            ssrc[nd * NHEAD + head0 + 1] = ps1;
            sdst[nd * NHEAD + head0 + 1] = pd1;
        }
    }
}

// ---------------------------------------------------------------------------
// Kernel 4: merged-head aggregation (unchanged from round 8/9).
// ---------------------------------------------------------------------------
__global__ __launch_bounds__(256) void aggregate(const short* __restrict__ xtb,
                                                 const float* __restrict__ ssrc,
                                                 const float* __restrict__ sdst,
                                                 const int* __restrict__ cnt,
                                                 const int* __restrict__ rowptr0,
                                                 const int* __restrict__ col,
                                                 const float* __restrict__ bias,
                                                 float* __restrict__ out) {
    __shared__ float wlds[4][NHEAD][68];
    __shared__ int   jlds[4][64];
    const int nb   = threadIdx.x >> 6;
    const int lane = threadIdx.x & 63;
    const int blk  = blockIdx.x;
    const int bidx = blk & 7;                                   // batch -> XCD
    const int i    = bidx * NNODE + (blk >> 3) * 4 + nb;
    const int n    = i & (NNODE - 1);
    const int deg  = cnt[n];
    const int start = bidx * NEDGE + rowptr0[n];
    const int h    = lane >> 3;
    const int sub  = lane & 7;
    float* wrow = &wlds[nb][0][0];
    int*   jrow = &jlds[nb][0];

    for (int t = lane; t < NHEAD * 68; t += 64) wrow[t] = 0.f;
    jrow[lane] = i;

    const float sdh = sdst[i * NHEAD + h];
    float selfv = ssrc[i * NHEAD + h] + sdh;
    selfv = selfv >= 0.f ? selfv : NEG_SLOPE * selfv;

    float m = selfv;
    for (int e = sub; e < deg; e += 8) {
        int j = col[start + e];
        float v = ssrc[j * NHEAD + h] + sdh;
        v = v >= 0.f ? v : NEG_SLOPE * v;
        if (e < 64) {
            wrow[h * 68 + e] = v;
            if (h == 0) jrow[e] = j;
        }
        m = fmaxf(m, v);
    }
    m = fmaxf(m, __shfl_xor(m, 4));
    m = fmaxf(m, __shfl_xor(m, 2));
    m = fmaxf(m, __shfl_xor(m, 1));

    float sp = 0.f;
    for (int e = sub; e < deg; e += 8) {
        float v;
        if (e < 64) {
            v = wrow[h * 68 + e];
        } else {
            int j = col[start + e];
            v = ssrc[j * NHEAD + h] + sdh;
            v = v >= 0.f ? v : NEG_SLOPE * v;
        }
        float w = __expf(v - m);
        if (e < 64) wrow[h * 68 + e] = w;
        sp += w;
    }
    sp += __shfl_xor(sp, 4); sp += __shfl_xor(sp, 2); sp += __shfl_xor(sp, 1);
    const float eself = __expf(selfv - m);
    const float inv = 1.f / (sp + eself + 1e-16f);

    const int c8 = lane * 8;
    float acc[8] = {};

    {
        bfrag xv = *(const bfrag*)&xtb[i * HC + c8];
#pragma unroll
        for (int k = 0; k < 8; ++k) acc[k] += eself * b2f(xv[k]);
    }

    const int degc = min(deg, 64);
    const int degp = (degc + 7) & ~7;
    for (int e0 = 0; e0 < degp; e0 += 8) {
        float4 wA = *(const float4*)&wrow[h * 68 + e0];
        float4 wB = *(const float4*)&wrow[h * 68 + e0 + 4];
        int4 jA = *(const int4*)&jrow[e0];
        int4 jB = *(const int4*)&jrow[e0 + 4];
        bfrag x0 = *(const bfrag*)&xtb[jA.x * HC + c8];
        bfrag x1 = *(const bfrag*)&xtb[jA.y * HC + c8];
        bfrag x2 = *(const bfrag*)&xtb[jA.z * HC + c8];
        bfrag x3 = *(const bfrag*)&xtb[jA.w * HC + c8];
        bfrag x4 = *(const bfrag*)&xtb[jB.x * HC + c8];
        bfrag x5 = *(const bfrag*)&xtb[jB.y * HC + c8];
        bfrag x6 = *(const bfrag*)&xtb[jB.z * HC + c8];
        bfrag x7 = *(const bfrag*)&xtb[jB.w * HC + c8];
#pragma unroll
        for (int k = 0; k < 8; ++k) {
            acc[k] += wA.x * b2f(x0[k]) + wA.y * b2f(x1[k]) +
                      wA.z * b2f(x2[k]) + wA.w * b2f(x3[k]) +
                      wB.x * b2f(x4[k]) + wB.y * b2f(x5[k]) +
                      wB.z * b2f(x6[k]) + wB.w * b2f(x7[k]);
        }
    }
    for (int e = 64; e < deg; ++e) {
        int j = col[start + e];
        float v = ssrc[j * NHEAD + h] + sdh;
        v = v >= 0.f ? v : NEG_SLOPE * v;
        float wv = __expf(v - m);
        bfrag xv = *(const bfrag*)&xtb[j * HC + c8];
#pragma unroll
        for (int k = 0; k < 8; ++k) acc[k] += wv * b2f(xv[k]);
    }

    const float4 b0 = *(const float4*)&bias[c8];
    const float4 b1 = *(const float4*)&bias[c8 + 4];
    float4 o0 = {acc[0] * inv + b0.x, acc[1] * inv + b0.y,
                 acc[2] * inv + b0.z, acc[3] * inv + b0.w};
    float4 o1 = {acc[4] * inv + b1.x, acc[5] * inv + b1.y,
                 acc[6] * inv + b1.z, acc[7] * inv + b1.w};
    *(float4*)&out[i * HC + c8]     = o0;
    *(float4*)&out[i * HC + c8 + 4] = o1;
}

// ---------------------------------------------------------------------------
extern "C" void kernel_launch(void* const* d_in, const int* in_sizes, int n_in,
                              void* d_out, int out_size, void* d_ws, size_t ws_size,
                              hipStream_t stream) {
    const float* x       = (const float*)d_in[0];
    const int*   ei      = (const int*)d_in[1];
    const float* W       = (const float*)d_in[2];
    const float* att_src = (const float*)d_in[3];
    const float* att_dst = (const float*)d_in[4];
    const float* bias    = (const float*)d_in[5];
    float* out = (float*)d_out;

    char* ws = (char*)d_ws;
    short* xtb      = (short*)(ws);                                // 16777216 B
    float* ssrc     = (float*)(ws + 16777216);                     // 524288 B
    float* sdst     = (float*)(ws + 17301504);                     // 524288 B
    int*   cnt      = (int*)(ws + 17825792);                       // 8192 B
    int*   rowptr0  = (int*)(ws + 17833984);                       // 8192 B
    int*   widx     = (int*)(ws + 17842176);                       // 65536 B
    int*   col      = (int*)(ws + 17907712);                       // 1048576 B
    short* WT       = (short*)(ws + 18956288);                     // 262144 B
    int*   cnt_part = (int*)(ws + 19218432);                       // 262144 B
                                                                   // total 19480576 B
    prep_kernel<<<128 + NHIST, 256, 0, stream>>>(W, ei, WT, cnt_part);
    scan_kernel<<<1, 256, 0, stream>>>(cnt_part, cnt, rowptr0, widx);
    gemm_scatter<<<GEMM_BLKS + 512, 512, 0, stream>>>(x, WT, xtb, att_src, att_dst,
                                                      ssrc, sdst, ei, widx, col);
    aggregate<<<BN_TOT / 4, 256, 0, stream>>>(xtb, ssrc, sdst, cnt, rowptr0, col, bias, out);
}

// Round 11
// 142.576 us; speedup vs baseline: 1.0682x; 1.0422x over previous
//
#include <hip/hip_runtime.h>
#include <hip/hip_bf16.h>

// Problem constants
#define BDIM 8
#define NNODE 2048
#define CIN 256
#define NEDGE 32768
#define NHEAD 8
#define COUT 64
#define HC 512            // NHEAD * COUT
#define BN_TOT 16384      // BDIM * NNODE
#define NEG_SLOPE 0.2f
#define NHIST 32          // partial-histogram blocks
#define GEMM_BLKS 256     // 64-row x 512-col tiles

typedef __hip_bfloat16 bf16;
typedef __attribute__((ext_vector_type(8))) short bfrag;   // 8 bf16 = 4 VGPRs
typedef __attribute__((ext_vector_type(4))) float ffrag;   // 4 fp32 acc

static __device__ __forceinline__ short f2b(float f) {
    __hip_bfloat16 h = __float2bfloat16(f);
    return *(short*)&h;
}
static __device__ __forceinline__ float b2f(short s) {
    return __uint_as_float(((unsigned)(unsigned short)s) << 16);
}
static __device__ __forceinline__ unsigned pack2(float a, float b) {
    return (unsigned)(unsigned short)f2b(a) | ((unsigned)(unsigned short)f2b(b) << 16);
}
// async global->LDS, 16B/lane; LDS dest = wave-uniform base + lane*16
static __device__ __forceinline__ void async_cp16(const short* gsrc, short* ldst) {
    __builtin_amdgcn_global_load_lds(
        (const __attribute__((address_space(1))) void*)gsrc,
        (__attribute__((address_space(3))) void*)ldst, 16, 0, 0);
}

// ---------------------------------------------------------------------------
// Kernel 1: blocks 0..127 transpose W -> WT bf16 [512][256];
// blocks 128..159: partial histograms of batch-0 dst (r8 structure).
// ---------------------------------------------------------------------------
__global__ __launch_bounds__(256) void prep_kernel(const float* __restrict__ W,
                                                   const int* __restrict__ ei,
                                                   short* __restrict__ WT,
                                                   int* __restrict__ cnt_part) {
    const int b = blockIdx.x;
    if (b < 128) {
        __shared__ float t[32][33];
        const int kt = b >> 4;
        const int nt = b & 15;
        const int tx = threadIdx.x & 31, ty = threadIdx.x >> 5;
#pragma unroll
        for (int i = 0; i < 4; ++i)
            t[ty + 8 * i][tx] = W[(kt * 32 + ty + 8 * i) * HC + nt * 32 + tx];
        __syncthreads();
#pragma unroll
        for (int i = 0; i < 4; ++i)
            WT[(nt * 32 + ty + 8 * i) * CIN + kt * 32 + tx] = f2b(t[tx][ty + 8 * i]);
    } else {
        __shared__ int hcnt[NNODE];
        const int p = b - 128;
        const int t = threadIdx.x;
        for (int k = t; k < NNODE; k += 256) hcnt[k] = 0;
        __syncthreads();
        const int* dst = ei + NEDGE;
        const int base = p * (NEDGE / NHIST);
#pragma unroll
        for (int k = 0; k < NEDGE / NHIST / 256; ++k)
            atomicAdd(&hcnt[dst[base + t + k * 256]], 1);
        __syncthreads();
        for (int k = t; k < NNODE; k += 256) cnt_part[k * NHIST + p] = hcnt[k];
    }
}

// ---------------------------------------------------------------------------
// Kernel 2: single-block CSR finalize. col is SHARED across batches now, so
// widx/rowptr0 are batch-0 only (NNODE entries).
// ---------------------------------------------------------------------------
__global__ __launch_bounds__(256) void scan_kernel(const int* __restrict__ cnt_part,
                                                   int* __restrict__ cnt,
                                                   int* __restrict__ rowptr0,
                                                   int* __restrict__ widx) {
    __shared__ int sums[256];
    const int t = threadIdx.x;
    int v[8];
    int tot = 0;
#pragma unroll
    for (int i = 0; i < 8; ++i) {
        const int n = t * 8 + i;
        int s = 0;
#pragma unroll
        for (int p4 = 0; p4 < NHIST; p4 += 4) {
            int4 c = *(const int4*)&cnt_part[n * NHIST + p4];
            s += c.x + c.y + c.z + c.w;
        }
        v[i] = s;
        tot += s;
    }
    sums[t] = tot;
    __syncthreads();
    for (int off = 1; off < 256; off <<= 1) {
        int xv = (t >= off) ? sums[t - off] : 0;
        __syncthreads();
        sums[t] += xv;
        __syncthreads();
    }
    int run = sums[t] - tot;
    int base[8];
#pragma unroll
    for (int i = 0; i < 8; ++i) { base[i] = run; run += v[i]; }
#pragma unroll
    for (int i = 0; i < 8; ++i) {
        const int n = t * 8 + i;
        cnt[n] = v[i];
        rowptr0[n] = base[i];
        widx[n] = base[i];
    }
}

// ---------------------------------------------------------------------------
// Kernel 3 (fused): blocks 0..255 = full-width GEMM tile (64 nodes x 512
// channels) reading fp32 x directly; blocks 256..319 = batch-0 edge scatter
// (32K edges only — graph is shared across batches; aggregate adds the
// batch offset at read time. 8x fewer atomics/writes than per-batch col).
// ---------------------------------------------------------------------------
__global__ __launch_bounds__(512, 2) void gemm_scatter(const float* __restrict__ x,
                                                       const short* __restrict__ WT,
                                                       short* __restrict__ xtb,
                                                       const float* __restrict__ att_src,
                                                       const float* __restrict__ att_dst,
                                                       float* __restrict__ ssrc,
                                                       float* __restrict__ sdst,
                                                       const int* __restrict__ ei,
                                                       int* __restrict__ widx,
                                                       int* __restrict__ col) {
    const int blk = blockIdx.x;
    if (blk >= GEMM_BLKS) {
        const int t = (blk - GEMM_BLKS) * 512 + threadIdx.x;   // 0..32767
        const int s = ei[t];
        const int d = ei[NEDGE + t];
        const int p = atomicAdd(&widx[d], 1);
        col[p] = s;                                            // batch-0 form
        return;
    }

    __shared__ __align__(16) short As[64 * 256];        // 32 KB
    __shared__ __align__(16) short Bs[2][512 * 32];     // 2 x 32 KB

    const int tid  = threadIdx.x;
    const int lane = tid & 63;
    const int w    = tid >> 6;            // 0..7
    const int row0 = blk * 64;
    const int wm   = (w & 1) * 32;        // row half (32 rows)
    const int wn   = (w >> 1) * 128;      // col quarter (128 ch = 2 heads)
    const int fm   = lane & 15;
    const int fq   = lane >> 4;

    // ---- stage A: fp32 x -> bf16 LDS (once) ----
    {
        const int r   = tid >> 3;             // 0..63
        const int kb0 = (tid & 7) * 8;        // 0..56
#pragma unroll
        for (int i = 0; i < 4; ++i) {
            const int kb = kb0 + i * 64;
            float4 v0 = *(const float4*)&x[(row0 + r) * CIN + kb];
            float4 v1 = *(const float4*)&x[(row0 + r) * CIN + kb + 4];
            bfrag o;
            o[0] = f2b(v0.x); o[1] = f2b(v0.y); o[2] = f2b(v0.z); o[3] = f2b(v0.w);
            o[4] = f2b(v1.x); o[5] = f2b(v1.y); o[6] = f2b(v1.z); o[7] = f2b(v1.w);
            *(bfrag*)&As[(((r >> 4) * 32 + (kb >> 3)) * 16 + (r & 15)) * 8] = o;
        }
    }

    // ---- first B chunk (k0 = 0) into buf 0 ----
    {
#pragma unroll
        for (int i2 = 0; i2 < 4; ++i2) {
            const int cb16 = w * 4 + i2;
            const int c = cb16 * 16 + (lane >> 2);
            async_cp16(&WT[c * CIN + (lane & 3) * 8], &Bs[0][cb16 * 512]);
        }
    }
    __syncthreads();   // A writes visible + chunk0 drained

    ffrag acc[8][2] = {};   // [ng][mg]

    for (int k8 = 0; k8 < 8; ++k8) {
        const int buf = k8 & 1;
        if (k8 < 7) {
            const int k0n = (k8 + 1) * 32;
#pragma unroll
            for (int i2 = 0; i2 < 4; ++i2) {
                const int cb16 = w * 4 + i2;
                const int c = cb16 * 16 + (lane >> 2);
                async_cp16(&WT[c * CIN + k0n + (lane & 3) * 8], &Bs[buf ^ 1][cb16 * 512]);
            }
        }
        bfrag af[2];
#pragma unroll
        for (int mg = 0; mg < 2; ++mg)
            af[mg] = *(const bfrag*)&As[((((wm >> 4) + mg) * 32 + k8 * 4 + fq) * 16 + fm) * 8];
#pragma unroll
        for (int ng = 0; ng < 8; ++ng) {
            bfrag bfr = *(const bfrag*)&Bs[buf][((((wn >> 4) + ng) * 16 + fm) * 4 + fq) * 8];
#pragma unroll
            for (int mg = 0; mg < 2; ++mg)
                acc[ng][mg] = __builtin_amdgcn_mfma_f32_16x16x32_bf16(
                    bfr, af[mg], acc[ng][mg], 0, 0, 0);
        }
        __syncthreads();
    }

    // ---- epilogue: packed bf16 stores + fused attention scores ----
    float4 s4[8], d4[8];
#pragma unroll
    for (int ng = 0; ng < 8; ++ng) {
        const int cb = wn + ng * 16 + fq * 4;
        s4[ng] = *(const float4*)&att_src[cb];
        d4[ng] = *(const float4*)&att_dst[cb];
    }
    const int head0 = wn >> 6;
#pragma unroll
    for (int mg = 0; mg < 2; ++mg) {
        const int nd = row0 + wm + mg * 16 + fm;
        float ps0 = 0.f, pd0 = 0.f, ps1 = 0.f, pd1 = 0.f;
#pragma unroll
        for (int ng = 0; ng < 8; ++ng) {
            const int cb = wn + ng * 16 + fq * 4;
            uint2 pk;
            pk.x = pack2(acc[ng][mg][0], acc[ng][mg][1]);
            pk.y = pack2(acc[ng][mg][2], acc[ng][mg][3]);
            *(uint2*)&xtb[nd * HC + cb] = pk;
            const float dot_s = acc[ng][mg][0] * s4[ng].x + acc[ng][mg][1] * s4[ng].y +
                                acc[ng][mg][2] * s4[ng].z + acc[ng][mg][3] * s4[ng].w;
            const float dot_d = acc[ng][mg][0] * d4[ng].x + acc[ng][mg][1] * d4[ng].y +
                                acc[ng][mg][2] * d4[ng].z + acc[ng][mg][3] * d4[ng].w;
            if (ng < 4) { ps0 += dot_s; pd0 += dot_d; }
            else        { ps1 += dot_s; pd1 += dot_d; }
        }
        ps0 += __shfl_xor(ps0, 16); ps0 += __shfl_xor(ps0, 32);
        pd0 += __shfl_xor(pd0, 16); pd0 += __shfl_xor(pd0, 32);
        ps1 += __shfl_xor(ps1, 16); ps1 += __shfl_xor(ps1, 32);
        pd1 += __shfl_xor(pd1, 16); pd1 += __shfl_xor(pd1, 32);
        if (lane < 16) {
            ssrc[nd * NHEAD + head0]     = ps0;
            sdst[nd * NHEAD + head0]     = pd0;
            ssrc[nd * NHEAD + head0 + 1] = ps1;
            sdst[nd * NHEAD + head0 + 1] = pd1;
        }
    }
}

// ---------------------------------------------------------------------------
// Kernel 4: merged-head aggregation. col is batch-0; j = bidx*NNODE + col[e].
// ---------------------------------------------------------------------------
__global__ __launch_bounds__(256) void aggregate(const short* __restrict__ xtb,
                                                 const float* __restrict__ ssrc,
                                                 const float* __restrict__ sdst,
                                                 const int* __restrict__ cnt,
                                                 const int* __restrict__ rowptr0,
                                                 const int* __restrict__ col,
                                                 const float* __restrict__ bias,
                                                 float* __restrict__ out) {
    __shared__ float wlds[4][NHEAD][68];
    __shared__ int   jlds[4][64];
    const int nb   = threadIdx.x >> 6;
    const int lane = threadIdx.x & 63;
    const int blk  = blockIdx.x;
    const int bidx = blk & 7;                                   // batch -> XCD
    const int boff = bidx * NNODE;
    const int i    = boff + (blk >> 3) * 4 + nb;
    const int n    = i & (NNODE - 1);
    const int deg  = cnt[n];
    const int start = rowptr0[n];                               // batch-0 CSR
    const int h    = lane >> 3;
    const int sub  = lane & 7;
    float* wrow = &wlds[nb][0][0];
    int*   jrow = &jlds[nb][0];

    for (int t = lane; t < NHEAD * 68; t += 64) wrow[t] = 0.f;
    jrow[lane] = i;

    const float sdh = sdst[i * NHEAD + h];
    float selfv = ssrc[i * NHEAD + h] + sdh;
    selfv = selfv >= 0.f ? selfv : NEG_SLOPE * selfv;

    // pass A: logits -> LDS, global source ids -> LDS, running max
    float m = selfv;
    for (int e = sub; e < deg; e += 8) {
        int j = boff + col[start + e];
        float v = ssrc[j * NHEAD + h] + sdh;
        v = v >= 0.f ? v : NEG_SLOPE * v;
        if (e < 64) {
            wrow[h * 68 + e] = v;
            if (h == 0) jrow[e] = j;
        }
        m = fmaxf(m, v);
    }
    m = fmaxf(m, __shfl_xor(m, 4));
    m = fmaxf(m, __shfl_xor(m, 2));
    m = fmaxf(m, __shfl_xor(m, 1));

    // pass B: exp, sum; overwrite LDS with unnormalized weights
    float sp = 0.f;
    for (int e = sub; e < deg; e += 8) {
        float v;
        if (e < 64) {
            v = wrow[h * 68 + e];
        } else {
            int j = boff + col[start + e];
            v = ssrc[j * NHEAD + h] + sdh;
            v = v >= 0.f ? v : NEG_SLOPE * v;
        }
        float w = __expf(v - m);
        if (e < 64) wrow[h * 68 + e] = w;
        sp += w;
    }
    sp += __shfl_xor(sp, 4); sp += __shfl_xor(sp, 2); sp += __shfl_xor(sp, 1);
    const float eself = __expf(selfv - m);
    const float inv = 1.f / (sp + eself + 1e-16f);

    const int c8 = lane * 8;
    float acc[8] = {};

    // self-loop
    {
        bfrag xv = *(const bfrag*)&xtb[i * HC + c8];
#pragma unroll
        for (int k = 0; k < 8; ++k) acc[k] += eself * b2f(xv[k]);
    }

    const int degc = min(deg, 64);
    const int degp = (degc + 7) & ~7;
    for (int e0 = 0; e0 < degp; e0 += 8) {
        float4 wA = *(const float4*)&wrow[h * 68 + e0];
        float4 wB = *(const float4*)&wrow[h * 68 + e0 + 4];
        int4 jA = *(const int4*)&jrow[e0];
        int4 jB = *(const int4*)&jrow[e0 + 4];
        bfrag x0 = *(const bfrag*)&xtb[jA.x * HC + c8];
        bfrag x1 = *(const bfrag*)&xtb[jA.y * HC + c8];
        bfrag x2 = *(const bfrag*)&xtb[jA.z * HC + c8];
        bfrag x3 = *(const bfrag*)&xtb[jA.w * HC + c8];
        bfrag x4 = *(const bfrag*)&xtb[jB.x * HC + c8];
        bfrag x5 = *(const bfrag*)&xtb[jB.y * HC + c8];
        bfrag x6 = *(const bfrag*)&xtb[jB.z * HC + c8];
        bfrag x7 = *(const bfrag*)&xtb[jB.w * HC + c8];
#pragma unroll
        for (int k = 0; k < 8; ++k) {
            acc[k] += wA.x * b2f(x0[k]) + wA.y * b2f(x1[k]) +
                      wA.z * b2f(x2[k]) + wA.w * b2f(x3[k]) +
                      wB.x * b2f(x4[k]) + wB.y * b2f(x5[k]) +
                      wB.z * b2f(x6[k]) + wB.w * b2f(x7[k]);
        }
    }
    // correctness fallback for deg > 64
    for (int e = 64; e < deg; ++e) {
        int j = boff + col[start + e];
        float v = ssrc[j * NHEAD + h] + sdh;
        v = v >= 0.f ? v : NEG_SLOPE * v;
        float wv = __expf(v - m);
        bfrag xv = *(const bfrag*)&xtb[j * HC + c8];
#pragma unroll
        for (int k = 0; k < 8; ++k) acc[k] += wv * b2f(xv[k]);
    }

    const float4 b0 = *(const float4*)&bias[c8];
    const float4 b1 = *(const float4*)&bias[c8 + 4];
    float4 o0 = {acc[0] * inv + b0.x, acc[1] * inv + b0.y,
                 acc[2] * inv + b0.z, acc[3] * inv + b0.w};
    float4 o1 = {acc[4] * inv + b1.x, acc[5] * inv + b1.y,
                 acc[6] * inv + b1.z, acc[7] * inv + b1.w};
    *(float4*)&out[i * HC + c8]     = o0;
    *(float4*)&out[i * HC + c8 + 4] = o1;
}

// ---------------------------------------------------------------------------
extern "C" void kernel_launch(void* const* d_in, const int* in_sizes, int n_in,
                              void* d_out, int out_size, void* d_ws, size_t ws_size,
                              hipStream_t stream) {
    const float* x       = (const float*)d_in[0];
    const int*   ei      = (const int*)d_in[1];
    const float* W       = (const float*)d_in[2];
    const float* att_src = (const float*)d_in[3];
    const float* att_dst = (const float*)d_in[4];
    const float* bias    = (const float*)d_in[5];
    float* out = (float*)d_out;

    char* ws = (char*)d_ws;
    short* xtb      = (short*)(ws);                                // 16777216 B
    float* ssrc     = (float*)(ws + 16777216);                     // 524288 B
    float* sdst     = (float*)(ws + 17301504);                     // 524288 B
    int*   cnt      = (int*)(ws + 17825792);                       // 8192 B
    int*   rowptr0  = (int*)(ws + 17833984);                       // 8192 B
    int*   widx     = (int*)(ws + 17842176);                       // 8192 B
    int*   col      = (int*)(ws + 17850368);                       // 131072 B
    short* WT       = (short*)(ws + 17981440);                     // 262144 B
    int*   cnt_part = (int*)(ws + 18243584);                       // 262144 B
                                                                   // total 18505728 B
    prep_kernel<<<128 + NHIST, 256, 0, stream>>>(W, ei, WT, cnt_part);
    scan_kernel<<<1, 256, 0, stream>>>(cnt_part, cnt, rowptr0, widx);
    gemm_scatter<<<GEMM_BLKS + 64, 512, 0, stream>>>(x, WT, xtb, att_src, att_dst,
                                                     ssrc, sdst, ei, widx, col);
    aggregate<<<BN_TOT / 4, 256, 0, stream>>>(xtb, ssrc, sdst, cnt, rowptr0, col, bias, out);
}